// Round 2
// baseline (1638.761 us; speedup 1.0000x reference)
//
#include <hip/hip_runtime.h>
#include <hip/hip_bf16.h>
#include <stdint.h>

// Problem constants
#define NN 100000
#define NE 1600000
#define DH 128
#define DOUT 32
#define NG 64
#define EPS 1e-5f

#define SCAN_BLK 1024
#define SCAN_NB ((NN + SCAN_BLK - 1) / SCAN_BLK)   // 98

typedef __attribute__((ext_vector_type(8))) unsigned short ushort8;

__device__ __forceinline__ float b2f(unsigned short u) {
    return __uint_as_float(((unsigned int)u) << 16);
}
__device__ __forceinline__ unsigned short f2b(float f) {   // round-to-nearest-even
    unsigned int u = __float_as_uint(f);
    unsigned int r = (u + 0x7fffu + ((u >> 16) & 1u)) >> 16;
    return (unsigned short)r;
}
__device__ __forceinline__ float blo(unsigned int v) { return __uint_as_float(v << 16); }
__device__ __forceinline__ float bhi(unsigned int v) { return __uint_as_float(v & 0xffff0000u); }

// ---------------- CSR build ----------------
// NOTE: harness passes integer inputs as int32.

__global__ void k_count(const int* __restrict__ ei, const int* __restrict__ batch,
                        int* __restrict__ cnt, int* __restrict__ gcnt) {
    int i = blockIdx.x * blockDim.x + threadIdx.x;
    int stride = gridDim.x * blockDim.x;
    for (int e = i; e < NE; e += stride) {
        int d = ei[NE + e];
        atomicAdd(&cnt[d], 1);
        if (e < NN) atomicAdd(&gcnt[batch[e]], 1);
    }
}

__global__ void k_scan_partial(const int* __restrict__ cnt, int* __restrict__ bsum) {
    __shared__ int sdata[256];
    int blk = blockIdx.x, t = threadIdx.x;
    int base = blk * SCAN_BLK + t * 4;
    int s = 0;
#pragma unroll
    for (int q = 0; q < 4; q++) { int idx = base + q; if (idx < NN) s += cnt[idx]; }
    sdata[t] = s; __syncthreads();
    for (int o = 128; o; o >>= 1) { if (t < o) sdata[t] += sdata[t + o]; __syncthreads(); }
    if (t == 0) bsum[blk] = sdata[0];
}

__global__ void k_scan_top(const int* __restrict__ bsum, int* __restrict__ bscan, int* __restrict__ rowptr) {
    if (threadIdx.x == 0) {
        int acc = 0;
        for (int b = 0; b < SCAN_NB; b++) { bscan[b] = acc; acc += bsum[b]; }
        rowptr[NN] = acc;   // == NE
    }
}

// writes rowptr, reuses cnt[] as the fill cursor, computes dinv
__global__ void k_scan_final(int* __restrict__ cnt, const int* __restrict__ bscan,
                             int* __restrict__ rowptr, float* __restrict__ dinv) {
    __shared__ int sdata[256];
    int blk = blockIdx.x, t = threadIdx.x;
    int base = blk * SCAN_BLK + t * 4;
    int v[4]; int s = 0;
#pragma unroll
    for (int q = 0; q < 4; q++) { int idx = base + q; v[q] = (idx < NN) ? cnt[idx] : 0; s += v[q]; }
    sdata[t] = s; __syncthreads();
    for (int o = 1; o < 256; o <<= 1) {
        int add = (t >= o) ? sdata[t - o] : 0;
        __syncthreads();
        sdata[t] += add;
        __syncthreads();
    }
    int offset = bscan[blk] + sdata[t] - s;   // exclusive prefix for this thread
#pragma unroll
    for (int q = 0; q < 4; q++) {
        int idx = base + q;
        if (idx < NN) {
            rowptr[idx] = offset;
            cnt[idx] = offset;                      // cursor for k_fill
            dinv[idx] = rsqrtf((float)(v[q] + 1));  // +1 self loop
            offset += v[q];
        }
    }
}

__global__ void k_fill(const int* __restrict__ ei, int* __restrict__ cursor, int* __restrict__ csr) {
    int i = blockIdx.x * blockDim.x + threadIdx.x;
    int stride = gridDim.x * blockDim.x;
    for (int e = i; e < NE; e += stride) {
        int s = ei[e];
        int d = ei[NE + e];
        int p = atomicAdd(&cursor[d], 1);
        csr[p] = s;
    }
}

// ---------------- GEMM: C[N,128](bf16) = transform(A)[N,128] @ W[128,128] ----------------
// AT=float: layer 1 (raw f32 input). AT=ushort(bf16): layer 2 with BN scale/shift + ReLU fused.

#define WSWZ(c4) ((c4) ^ (((c4) >> 3) & 3))

template <bool BN, typename AT>
__global__ __launch_bounds__(256) void k_gemm(const AT* __restrict__ A, const float* __restrict__ W,
                                              unsigned short* __restrict__ C,
                                              const float* __restrict__ scale, const float* __restrict__ shift) {
    __shared__ float As[64][132];
    __shared__ float Ws[32][128];
    int row0 = blockIdx.x * 64;
    int t = threadIdx.x;
    int tx = t & 15, ty = t >> 4;

    // stage A tile: 64 rows x 128 cols
    if constexpr (sizeof(AT) == 4) {
        int r = t >> 5;      // 0..7
        int k4 = t & 31;     // float4 col index
#pragma unroll
        for (int p = 0; p < 8; p++) {
            int rr = p * 8 + r;
            int grow = row0 + rr;
            float4 v = make_float4(0.f, 0.f, 0.f, 0.f);
            if (grow < NN) v = reinterpret_cast<const float4*>(A)[(size_t)grow * 32 + k4];
            *reinterpret_cast<float4*>(&As[rr][k4 * 4]) = v;
        }
    } else {
        int r = t >> 4;      // 0..15
        int c8 = t & 15;     // ushort8 col chunk
#pragma unroll
        for (int p = 0; p < 4; p++) {
            int rr = p * 16 + r;
            int grow = row0 + rr;
            ushort8 v = (ushort8)0;
            if (grow < NN) v = reinterpret_cast<const ushort8*>(A)[(size_t)grow * 16 + c8];
#pragma unroll
            for (int q = 0; q < 8; q++) {
                float f = b2f(v[q]);
                if (BN) { int k = c8 * 8 + q; f = fmaxf(f * scale[k] + shift[k], 0.f); }
                As[rr][c8 * 8 + q] = f;
            }
        }
    }

    float acc[4][8];
#pragma unroll
    for (int i = 0; i < 4; i++)
#pragma unroll
        for (int q = 0; q < 8; q++) acc[i][q] = 0.f;

    for (int kc = 0; kc < 4; kc++) {
        __syncthreads();
        {
            int wr = t >> 5;
            int c4 = t & 31;
#pragma unroll
            for (int p = 0; p < 4; p++) {
                int rr = p * 8 + wr;
                float4 v = reinterpret_cast<const float4*>(W)[(size_t)(kc * 32 + rr) * 32 + c4];
                *reinterpret_cast<float4*>(&Ws[rr][WSWZ(c4) * 4]) = v;
            }
        }
        __syncthreads();
#pragma unroll
        for (int kk = 0; kk < 32; kk++) {
            int k = kc * 32 + kk;
            float a0 = As[ty * 4 + 0][k];
            float a1 = As[ty * 4 + 1][k];
            float a2 = As[ty * 4 + 2][k];
            float a3 = As[ty * 4 + 3][k];
            float4 w0 = *reinterpret_cast<const float4*>(&Ws[kk][WSWZ(tx * 2) * 4]);
            float4 w1 = *reinterpret_cast<const float4*>(&Ws[kk][WSWZ(tx * 2 + 1) * 4]);
            acc[0][0] += a0 * w0.x; acc[0][1] += a0 * w0.y; acc[0][2] += a0 * w0.z; acc[0][3] += a0 * w0.w;
            acc[0][4] += a0 * w1.x; acc[0][5] += a0 * w1.y; acc[0][6] += a0 * w1.z; acc[0][7] += a0 * w1.w;
            acc[1][0] += a1 * w0.x; acc[1][1] += a1 * w0.y; acc[1][2] += a1 * w0.z; acc[1][3] += a1 * w0.w;
            acc[1][4] += a1 * w1.x; acc[1][5] += a1 * w1.y; acc[1][6] += a1 * w1.z; acc[1][7] += a1 * w1.w;
            acc[2][0] += a2 * w0.x; acc[2][1] += a2 * w0.y; acc[2][2] += a2 * w0.z; acc[2][3] += a2 * w0.w;
            acc[2][4] += a2 * w1.x; acc[2][5] += a2 * w1.y; acc[2][6] += a2 * w1.z; acc[2][7] += a2 * w1.w;
            acc[3][0] += a3 * w0.x; acc[3][1] += a3 * w0.y; acc[3][2] += a3 * w0.z; acc[3][3] += a3 * w0.w;
            acc[3][4] += a3 * w1.x; acc[3][5] += a3 * w1.y; acc[3][6] += a3 * w1.z; acc[3][7] += a3 * w1.w;
        }
    }

#pragma unroll
    for (int i = 0; i < 4; i++) {
        int grow = row0 + ty * 4 + i;
        if (grow < NN) {
            ushort8 o;
#pragma unroll
            for (int q = 0; q < 8; q++) o[q] = f2b(acc[i][q]);
            reinterpret_cast<ushort8*>(C)[(size_t)grow * 16 + tx] = o;
        }
    }
}

// ---------------- Aggregation (bf16 h): agg[i] = dinv[i]*(sum_e dinv[src]h[src] + dinv[i]h[i]); + BN stats ----------------
// block = 128 threads = 2 waves; each wave owns a node stream; lane l handles features (2l, 2l+1) via one dword load.

__global__ __launch_bounds__(128) void k_aggregate(const unsigned short* __restrict__ h, const int* __restrict__ rowptr,
                                                   const int* __restrict__ csr, const float* __restrict__ dinv,
                                                   unsigned short* __restrict__ agg, float* __restrict__ stats) {
    int lane = threadIdx.x & 63;
    int wv = threadIdx.x >> 6;
    const unsigned int* h32 = reinterpret_cast<const unsigned int*>(h);
    float sum0 = 0.f, sum1 = 0.f, sq0 = 0.f, sq1 = 0.f;
    for (int i = blockIdx.x * 2 + wv; i < NN; i += gridDim.x * 2) {
        int row = rowptr[i], end = rowptr[i + 1];
        float di = dinv[i];
        unsigned int hv = h32[(size_t)i * 64 + lane];
        float a0 = di * blo(hv);
        float a1 = di * bhi(hv);
        int e = row;
        for (; e + 4 <= end; e += 4) {
            int n0 = csr[e], n1 = csr[e + 1], n2 = csr[e + 2], n3 = csr[e + 3];
            float d0 = dinv[n0], d1 = dinv[n1], d2 = dinv[n2], d3 = dinv[n3];
            unsigned int v0 = h32[(size_t)n0 * 64 + lane];
            unsigned int v1 = h32[(size_t)n1 * 64 + lane];
            unsigned int v2 = h32[(size_t)n2 * 64 + lane];
            unsigned int v3 = h32[(size_t)n3 * 64 + lane];
            a0 += d0 * blo(v0) + d1 * blo(v1) + d2 * blo(v2) + d3 * blo(v3);
            a1 += d0 * bhi(v0) + d1 * bhi(v1) + d2 * bhi(v2) + d3 * bhi(v3);
        }
        for (; e < end; e++) {
            int s = csr[e];
            float d = dinv[s];
            unsigned int v = h32[(size_t)s * 64 + lane];
            a0 += d * blo(v); a1 += d * bhi(v);
        }
        a0 *= di; a1 *= di;
        unsigned int o = (unsigned int)f2b(a0) | ((unsigned int)f2b(a1) << 16);
        reinterpret_cast<unsigned int*>(agg)[(size_t)i * 64 + lane] = o;
        sum0 += a0; sq0 += a0 * a0; sum1 += a1; sq1 += a1 * a1;
    }
    atomicAdd(&stats[lane * 2 + 0], sum0);
    atomicAdd(&stats[lane * 2 + 1], sum1);
    atomicAdd(&stats[DH + lane * 2 + 0], sq0);
    atomicAdd(&stats[DH + lane * 2 + 1], sq1);
}

__global__ void k_bnparams(const float* __restrict__ stats, const float* __restrict__ gamma,
                           const float* __restrict__ beta, float* __restrict__ scale, float* __restrict__ shift) {
    int j = threadIdx.x;
    float mu = stats[j] * (1.f / NN);
    float var = stats[DH + j] * (1.f / NN) - mu * mu;
    float rs = rsqrtf(var + EPS);
    float sc = rs * gamma[j];
    scale[j] = sc;
    shift[j] = beta[j] - mu * sc;
}

// ---------------- Pool: per-graph sums of relu(bn2(agg)) over sorted batch ids ----------------

#define POOL_CHUNK 64

__global__ __launch_bounds__(128) void k_pool(const unsigned short* __restrict__ agg, const int* __restrict__ batch,
                                              const float* __restrict__ scale, const float* __restrict__ shift,
                                              float* __restrict__ pooled) {
    int j = threadIdx.x;
    int n0 = blockIdx.x * POOL_CHUNK;
    int n1 = n0 + POOL_CHUNK; if (n1 > NN) n1 = NN;
    float sc = scale[j], sh = shift[j];
    int gcur = batch[n0];
    float acc = 0.f;
    for (int i = n0; i < n1; i++) {
        int g = batch[i];
        if (g != gcur) { atomicAdd(&pooled[(size_t)gcur * DH + j], acc); acc = 0.f; gcur = g; }
        float v = fmaxf(b2f(agg[(size_t)i * DH + j]) * sc + sh, 0.f);
        acc += v;
    }
    atomicAdd(&pooled[(size_t)gcur * DH + j], acc);
}

// ---------------- Head ----------------

__global__ __launch_bounds__(128) void k_head(const float* __restrict__ pooled, const int* __restrict__ gcnt,
                                              const float* __restrict__ fw1, const float* __restrict__ fb1,
                                              const float* __restrict__ fw2, const float* __restrict__ fb2,
                                              float* __restrict__ out) {
    __shared__ float p[DH];
    __shared__ float z[DH];
    int g = blockIdx.x;
    int j = threadIdx.x;
    float cnt = (float)max(gcnt[g], 1);
    p[j] = pooled[(size_t)g * DH + j] / cnt;
    __syncthreads();
    float a = fb1[j];
    for (int k = 0; k < DH; k++) a += p[k] * fw1[k * DH + j];
    z[j] = fmaxf(a, 0.f);
    __syncthreads();
    if (j < DOUT) {
        float l = fb2[j];
        for (int k = 0; k < DH; k++) l += z[k] * fw2[k * DOUT + j];
        float m = l;
        for (int o = 16; o; o >>= 1) m = fmaxf(m, __shfl_xor(m, o, 32));
        float e = expf(l - m);
        float s = e;
        for (int o = 16; o; o >>= 1) s += __shfl_xor(s, o, 32);
        out[(size_t)g * DOUT + j] = e / s;
    }
}

// ---------------- launch ----------------

static inline char* align256p(char* p) {
    return (char*)(((uintptr_t)p + 255) & ~(uintptr_t)255);
}

extern "C" void kernel_launch(void* const* d_in, const int* in_sizes, int n_in,
                              void* d_out, int out_size, void* d_ws, size_t ws_size,
                              hipStream_t stream) {
    const float* x     = (const float*)d_in[0];
    const int*   ei    = (const int*)d_in[1];    // int32 per harness convention
    const int*   batch = (const int*)d_in[2];
    const float* W1    = (const float*)d_in[3];
    const float* W2    = (const float*)d_in[5];
    const float* g1    = (const float*)d_in[7];
    const float* be1   = (const float*)d_in[8];
    const float* g2    = (const float*)d_in[9];
    const float* be2   = (const float*)d_in[10];
    const float* fw1   = (const float*)d_in[11];
    const float* fb1   = (const float*)d_in[12];
    const float* fw2   = (const float*)d_in[13];
    const float* fb2   = (const float*)d_in[14];
    float* out = (float*)d_out;

    // workspace carve-up (bf16 intermediates -> ~59 MB total)
    char* w = (char*)d_ws;
    unsigned short* hbuf = (unsigned short*)w;  w += (size_t)NN * DH * 2;
    unsigned short* abuf = (unsigned short*)w;  w += (size_t)NN * DH * 2;
    int*   csr    = (int*)w;    w += (size_t)NE * 4;
    int*   rowptr = (int*)w;    w += (size_t)(NN + 1) * 4;  w = align256p(w);
    float* dinv   = (float*)w;  w += (size_t)NN * 4;
    int*   bsum   = (int*)w;    w += 512 * 4;
    int*   bscan  = (int*)w;    w += 512 * 4;
    float* scale1 = (float*)w;  w += DH * 4;
    float* shift1 = (float*)w;  w += DH * 4;
    float* scale2 = (float*)w;  w += DH * 4;
    float* shift2 = (float*)w;  w += DH * 4;
    w = align256p(w);
    char* zstart  = w;
    int*   cnt    = (int*)w;    w += (size_t)NN * 4;   // also the fill cursor
    int*   gcnt   = (int*)w;    w += 64 * 4;
    float* stats1 = (float*)w;  w += 256 * 4;
    float* stats2 = (float*)w;  w += 256 * 4;
    float* pooled = (float*)w;  w += (size_t)NG * DH * 4;
    size_t zbytes = (size_t)(w - zstart);
    size_t need = (size_t)(w - (char*)d_ws);
    if (ws_size < need) return;   // diagnostic: clean absmax-fail instead of a fault

    hipMemsetAsync(zstart, 0, zbytes, stream);

    k_count<<<2048, 256, 0, stream>>>(ei, batch, cnt, gcnt);
    k_scan_partial<<<SCAN_NB, 256, 0, stream>>>(cnt, bsum);
    k_scan_top<<<1, 64, 0, stream>>>(bsum, bscan, rowptr);
    k_scan_final<<<SCAN_NB, 256, 0, stream>>>(cnt, bscan, rowptr, dinv);
    k_fill<<<2048, 256, 0, stream>>>(ei, cnt, csr);

    int gemm_grid = (NN + 63) / 64;

    // layer 1
    k_gemm<false, float><<<gemm_grid, 256, 0, stream>>>(x, W1, hbuf, nullptr, nullptr);
    k_aggregate<<<4096, 128, 0, stream>>>(hbuf, rowptr, csr, dinv, abuf, stats1);
    k_bnparams<<<1, 128, 0, stream>>>(stats1, g1, be1, scale1, shift1);

    // layer 2 (BN1+ReLU fused into GEMM A-load)
    k_gemm<true, unsigned short><<<gemm_grid, 256, 0, stream>>>(abuf, W2, hbuf, scale1, shift1);
    k_aggregate<<<4096, 128, 0, stream>>>(hbuf, rowptr, csr, dinv, abuf, stats2);
    k_bnparams<<<1, 128, 0, stream>>>(stats2, g2, be2, scale2, shift2);

    // pool (BN2+ReLU fused) + head
    int pool_grid = (NN + POOL_CHUNK - 1) / POOL_CHUNK;
    k_pool<<<pool_grid, 128, 0, stream>>>(abuf, batch, scale2, shift2, pooled);
    k_head<<<NG, 128, 0, stream>>>(pooled, gcnt, fw1, fb1, fw2, fb2, out);
}

// Round 3
// 604.202 us; speedup vs baseline: 2.7123x; 2.7123x over previous
//
#include <hip/hip_runtime.h>
#include <hip/hip_bf16.h>
#include <stdint.h>

// Problem constants
#define NN 100000
#define NE 1600000
#define DH 128
#define DOUT 32
#define NG 64
#define EPS 1e-5f

#define SCAN_BLK 1024
#define SCAN_NB ((NN + SCAN_BLK - 1) / SCAN_BLK)   // 98
#define NBUCKET 32

typedef __attribute__((ext_vector_type(8))) unsigned short ushort8;

__device__ __forceinline__ float b2f(unsigned short u) {
    return __uint_as_float(((unsigned int)u) << 16);
}
__device__ __forceinline__ unsigned int f2b(float f) {   // round-to-nearest-even, returns in low 16
    unsigned int u = __float_as_uint(f);
    return (u + 0x7fffu + ((u >> 16) & 1u)) >> 16;
}
__device__ __forceinline__ float blo(unsigned int v) { return __uint_as_float(v << 16); }
__device__ __forceinline__ float bhi(unsigned int v) { return __uint_as_float(v & 0xffff0000u); }

// ---------------- CSR build ----------------

__global__ void k_count(const int* __restrict__ ei_dst, int* __restrict__ cnt) {
    int i = blockIdx.x * blockDim.x + threadIdx.x;
    int stride = gridDim.x * blockDim.x;
    const int4* d4 = reinterpret_cast<const int4*>(ei_dst);
    for (int e = i; e < NE / 4; e += stride) {
        int4 d = d4[e];
        atomicAdd(&cnt[d.x], 1);
        atomicAdd(&cnt[d.y], 1);
        atomicAdd(&cnt[d.z], 1);
        atomicAdd(&cnt[d.w], 1);
    }
}

__global__ void k_gbound(const int* __restrict__ batch, int* __restrict__ first, int* __restrict__ last) {
    int i = blockIdx.x * blockDim.x + threadIdx.x;
    if (i >= NN) return;
    int g = batch[i];
    if (i == 0 || batch[i - 1] != g) first[g] = i;
    if (i == NN - 1 || batch[i + 1] != g) last[g] = i + 1;
}

__global__ void k_scan_partial(const int* __restrict__ cnt, int* __restrict__ bsum) {
    __shared__ int sdata[256];
    int blk = blockIdx.x, t = threadIdx.x;
    int base = blk * SCAN_BLK + t * 4;
    int s = 0;
#pragma unroll
    for (int q = 0; q < 4; q++) { int idx = base + q; if (idx < NN) s += cnt[idx]; }
    sdata[t] = s; __syncthreads();
    for (int o = 128; o; o >>= 1) { if (t < o) sdata[t] += sdata[t + o]; __syncthreads(); }
    if (t == 0) bsum[blk] = sdata[0];
}

__global__ void k_scan_top(const int* __restrict__ bsum, int* __restrict__ bscan, int* __restrict__ rowptr,
                           const int* __restrict__ first, const int* __restrict__ last, int* __restrict__ gcnt) {
    __shared__ int sd[128];
    int t = threadIdx.x;
    int v = (t < SCAN_NB) ? bsum[t] : 0;
    sd[t] = v; __syncthreads();
    for (int o = 1; o < 128; o <<= 1) {
        int add = (t >= o) ? sd[t - o] : 0;
        __syncthreads();
        sd[t] += add;
        __syncthreads();
    }
    if (t < SCAN_NB) bscan[t] = sd[t] - v;
    if (t == 127) rowptr[NN] = sd[127];
    if (t < NG) gcnt[t] = last[t] - first[t];
}

// writes rowptr, reuses cnt[] as the fill cursor, computes dinv
__global__ void k_scan_final(int* __restrict__ cnt, const int* __restrict__ bscan,
                             int* __restrict__ rowptr, float* __restrict__ dinv) {
    __shared__ int sdata[256];
    int blk = blockIdx.x, t = threadIdx.x;
    int base = blk * SCAN_BLK + t * 4;
    int v[4]; int s = 0;
#pragma unroll
    for (int q = 0; q < 4; q++) { int idx = base + q; v[q] = (idx < NN) ? cnt[idx] : 0; s += v[q]; }
    sdata[t] = s; __syncthreads();
    for (int o = 1; o < 256; o <<= 1) {
        int add = (t >= o) ? sdata[t - o] : 0;
        __syncthreads();
        sdata[t] += add;
        __syncthreads();
    }
    int offset = bscan[blk] + sdata[t] - s;
#pragma unroll
    for (int q = 0; q < 4; q++) {
        int idx = base + q;
        if (idx < NN) {
            rowptr[idx] = offset;
            cnt[idx] = offset;                      // cursor for k_fill
            dinv[idx] = rsqrtf((float)(v[q] + 1));  // +1 self loop
            offset += v[q];
        }
    }
}

__global__ void k_fill(const int* __restrict__ ei, int* __restrict__ cursor, int* __restrict__ csr) {
    int i = blockIdx.x * blockDim.x + threadIdx.x;
    int stride = gridDim.x * blockDim.x;
    const int4* s4 = reinterpret_cast<const int4*>(ei);
    const int4* d4 = reinterpret_cast<const int4*>(ei + NE);
    for (int e = i; e < NE / 4; e += stride) {
        int4 s = s4[e];
        int4 d = d4[e];
        csr[atomicAdd(&cursor[d.x], 1)] = s.x;
        csr[atomicAdd(&cursor[d.y], 1)] = s.y;
        csr[atomicAdd(&cursor[d.z], 1)] = s.z;
        csr[atomicAdd(&cursor[d.w], 1)] = s.w;
    }
}

// ---------------- GEMM: C[N,128](bf16) = rowscale * (transform(A)[N,128] @ W[128,128]) ----------------
// AT=float: layer 1 (raw f32 input). AT=ushort(bf16): layer 2 with BN scale/shift + ReLU fused on A-load.
// Output row i is scaled by rowscale[i] (= dinv[i]) so the aggregate gather needs no dinv reads.

#define WSWZ(c4) ((c4) ^ (((c4) >> 3) & 3))

template <bool BN, typename AT>
__global__ __launch_bounds__(256) void k_gemm(const AT* __restrict__ A, const float* __restrict__ W,
                                              unsigned short* __restrict__ C, const float* __restrict__ rowscale,
                                              const float* __restrict__ scale, const float* __restrict__ shift) {
    __shared__ float As[64][132];
    __shared__ float Ws[32][128];
    int row0 = blockIdx.x * 64;
    int t = threadIdx.x;
    int tx = t & 15, ty = t >> 4;

    if constexpr (sizeof(AT) == 4) {
        int r = t >> 5;
        int k4 = t & 31;
#pragma unroll
        for (int p = 0; p < 8; p++) {
            int rr = p * 8 + r;
            int grow = row0 + rr;
            float4 v = make_float4(0.f, 0.f, 0.f, 0.f);
            if (grow < NN) v = reinterpret_cast<const float4*>(A)[(size_t)grow * 32 + k4];
            *reinterpret_cast<float4*>(&As[rr][k4 * 4]) = v;
        }
    } else {
        int r = t >> 4;
        int c8 = t & 15;
#pragma unroll
        for (int p = 0; p < 4; p++) {
            int rr = p * 16 + r;
            int grow = row0 + rr;
            ushort8 v = (ushort8)0;
            if (grow < NN) v = reinterpret_cast<const ushort8*>(A)[(size_t)grow * 16 + c8];
#pragma unroll
            for (int q = 0; q < 8; q++) {
                float f = b2f(v[q]);
                if (BN) { int k = c8 * 8 + q; f = fmaxf(f * scale[k] + shift[k], 0.f); }
                As[rr][c8 * 8 + q] = f;
            }
        }
    }

    float acc[4][8];
#pragma unroll
    for (int i = 0; i < 4; i++)
#pragma unroll
        for (int q = 0; q < 8; q++) acc[i][q] = 0.f;

    for (int kc = 0; kc < 4; kc++) {
        __syncthreads();
        {
            int wr = t >> 5;
            int c4 = t & 31;
#pragma unroll
            for (int p = 0; p < 4; p++) {
                int rr = p * 8 + wr;
                float4 v = reinterpret_cast<const float4*>(W)[(size_t)(kc * 32 + rr) * 32 + c4];
                *reinterpret_cast<float4*>(&Ws[rr][WSWZ(c4) * 4]) = v;
            }
        }
        __syncthreads();
#pragma unroll
        for (int kk = 0; kk < 32; kk++) {
            int k = kc * 32 + kk;
            float a0 = As[ty * 4 + 0][k];
            float a1 = As[ty * 4 + 1][k];
            float a2 = As[ty * 4 + 2][k];
            float a3 = As[ty * 4 + 3][k];
            float4 w0 = *reinterpret_cast<const float4*>(&Ws[kk][WSWZ(tx * 2) * 4]);
            float4 w1 = *reinterpret_cast<const float4*>(&Ws[kk][WSWZ(tx * 2 + 1) * 4]);
            acc[0][0] += a0 * w0.x; acc[0][1] += a0 * w0.y; acc[0][2] += a0 * w0.z; acc[0][3] += a0 * w0.w;
            acc[0][4] += a0 * w1.x; acc[0][5] += a0 * w1.y; acc[0][6] += a0 * w1.z; acc[0][7] += a0 * w1.w;
            acc[1][0] += a1 * w0.x; acc[1][1] += a1 * w0.y; acc[1][2] += a1 * w0.z; acc[1][3] += a1 * w0.w;
            acc[1][4] += a1 * w1.x; acc[1][5] += a1 * w1.y; acc[1][6] += a1 * w1.z; acc[1][7] += a1 * w1.w;
            acc[2][0] += a2 * w0.x; acc[2][1] += a2 * w0.y; acc[2][2] += a2 * w0.z; acc[2][3] += a2 * w0.w;
            acc[2][4] += a2 * w1.x; acc[2][5] += a2 * w1.y; acc[2][6] += a2 * w1.z; acc[2][7] += a2 * w1.w;
            acc[3][0] += a3 * w0.x; acc[3][1] += a3 * w0.y; acc[3][2] += a3 * w0.z; acc[3][3] += a3 * w0.w;
            acc[3][4] += a3 * w1.x; acc[3][5] += a3 * w1.y; acc[3][6] += a3 * w1.z; acc[3][7] += a3 * w1.w;
        }
    }

#pragma unroll
    for (int i = 0; i < 4; i++) {
        int grow = row0 + ty * 4 + i;
        if (grow < NN) {
            float rs = rowscale[grow];
            ushort8 o;
#pragma unroll
            for (int q = 0; q < 8; q++) o[q] = (unsigned short)f2b(acc[i][q] * rs);
            reinterpret_cast<ushort8*>(C)[(size_t)grow * 16 + tx] = o;
        }
    }
}

// ---------------- Aggregation (hscaled bf16): agg[i] = dinv[i]*(hs[i] + sum_e hs[src]); + bucketed BN stats ----
// 128 threads = 2 waves. Within a wave: half-wave 0/1 process alternate edges (two rows per load instr);
// lane sl=lane&31 owns features 4sl..4sl+3 via one uint2 (8 B) load.

__global__ __launch_bounds__(128) void k_aggregate(const unsigned short* __restrict__ h, const int* __restrict__ rowptr,
                                                   const int* __restrict__ csr, const float* __restrict__ dinv,
                                                   unsigned short* __restrict__ agg, float* __restrict__ stats) {
    int lane = threadIdx.x & 63;
    int wv = threadIdx.x >> 6;
    int half = lane >> 5;
    int sl = lane & 31;
    const uint2* h64 = reinterpret_cast<const uint2*>(h);
    uint2* agg64 = reinterpret_cast<uint2*>(agg);
    float s0 = 0.f, s1 = 0.f, s2 = 0.f, s3 = 0.f;
    float q0 = 0.f, q1 = 0.f, q2 = 0.f, q3 = 0.f;
    int wid = blockIdx.x * 2 + wv;
    int nw = gridDim.x * 2;
    for (int i = wid; i < NN; i += nw) {
        int row = rowptr[i], end = rowptr[i + 1];
        int len = end - row;
        float di = dinv[i];
        float a0 = 0.f, a1 = 0.f, a2 = 0.f, a3 = 0.f;
        if (half == 0) {
            uint2 sv = h64[(size_t)i * 32 + sl];
            a0 = blo(sv.x); a1 = bhi(sv.x); a2 = blo(sv.y); a3 = bhi(sv.y);
        }
        int hc = (len + 1 - half) >> 1;   // this half-stream's edge count
        for (int t = 0; t < hc; t += 4) {
            bool k1 = (t + 1) < hc, k2 = (t + 2) < hc, k3 = (t + 3) < hc;
            int eA = row + (t << 1) + half;
            int eB = k1 ? eA + 2 : row;
            int eC = k2 ? eA + 4 : row;
            int eD = k3 ? eA + 6 : row;
            int n0 = csr[eA], n1 = csr[eB], n2 = csr[eC], n3 = csr[eD];
            uint2 v0 = h64[(size_t)n0 * 32 + sl];
            uint2 v1 = h64[(size_t)n1 * 32 + sl];
            uint2 v2 = h64[(size_t)n2 * 32 + sl];
            uint2 v3 = h64[(size_t)n3 * 32 + sl];
            a0 += blo(v0.x); a1 += bhi(v0.x); a2 += blo(v0.y); a3 += bhi(v0.y);
            a0 += k1 ? blo(v1.x) : 0.f; a1 += k1 ? bhi(v1.x) : 0.f;
            a2 += k1 ? blo(v1.y) : 0.f; a3 += k1 ? bhi(v1.y) : 0.f;
            a0 += k2 ? blo(v2.x) : 0.f; a1 += k2 ? bhi(v2.x) : 0.f;
            a2 += k2 ? blo(v2.y) : 0.f; a3 += k2 ? bhi(v2.y) : 0.f;
            a0 += k3 ? blo(v3.x) : 0.f; a1 += k3 ? bhi(v3.x) : 0.f;
            a2 += k3 ? blo(v3.y) : 0.f; a3 += k3 ? bhi(v3.y) : 0.f;
        }
        // combine the two half-wave partial sums
        a0 += __shfl_xor(a0, 32);
        a1 += __shfl_xor(a1, 32);
        a2 += __shfl_xor(a2, 32);
        a3 += __shfl_xor(a3, 32);
        a0 *= di; a1 *= di; a2 *= di; a3 *= di;
        if (half == 0) {
            uint2 o;
            o.x = f2b(a0) | (f2b(a1) << 16);
            o.y = f2b(a2) | (f2b(a3) << 16);
            agg64[(size_t)i * 32 + sl] = o;
            s0 += a0; q0 += a0 * a0;
            s1 += a1; q1 += a1 * a1;
            s2 += a2; q2 += a2 * a2;
            s3 += a3; q3 += a3 * a3;
        }
    }
    if (half == 0) {
        float* b = stats + (size_t)(wid & (NBUCKET - 1)) * 256;
        atomicAdd(&b[sl * 4 + 0], s0);
        atomicAdd(&b[sl * 4 + 1], s1);
        atomicAdd(&b[sl * 4 + 2], s2);
        atomicAdd(&b[sl * 4 + 3], s3);
        atomicAdd(&b[128 + sl * 4 + 0], q0);
        atomicAdd(&b[128 + sl * 4 + 1], q1);
        atomicAdd(&b[128 + sl * 4 + 2], q2);
        atomicAdd(&b[128 + sl * 4 + 3], q3);
    }
}

__global__ void k_bnparams(const float* __restrict__ stats, const float* __restrict__ gamma,
                           const float* __restrict__ beta, float* __restrict__ scale, float* __restrict__ shift) {
    int j = threadIdx.x;
    float su = 0.f, sq = 0.f;
    for (int b = 0; b < NBUCKET; b++) { su += stats[b * 256 + j]; sq += stats[b * 256 + 128 + j]; }
    float mu = su * (1.f / NN);
    float var = sq * (1.f / NN) - mu * mu;
    float rs = rsqrtf(var + EPS);
    float sc = rs * gamma[j];
    scale[j] = sc;
    shift[j] = beta[j] - mu * sc;
}

// ---------------- Pool: per-graph sums of relu(bn2(agg)) over sorted batch ids ----------------

#define POOL_CHUNK 64

__global__ __launch_bounds__(64) void k_pool(const unsigned short* __restrict__ agg, const int* __restrict__ batch,
                                             const float* __restrict__ scale, const float* __restrict__ shift,
                                             float* __restrict__ pooled) {
    int j = threadIdx.x;               // feature pair index (2j, 2j+1)
    const unsigned int* a32 = reinterpret_cast<const unsigned int*>(agg);
    int n0 = blockIdx.x * POOL_CHUNK;
    int n1 = n0 + POOL_CHUNK; if (n1 > NN) n1 = NN;
    float sc0 = scale[j * 2], sh0 = shift[j * 2];
    float sc1 = scale[j * 2 + 1], sh1 = shift[j * 2 + 1];
    int gcur = batch[n0];
    float acc0 = 0.f, acc1 = 0.f;
    for (int i = n0; i < n1; i++) {
        int g = batch[i];
        if (g != gcur) {
            atomicAdd(&pooled[(size_t)gcur * DH + j * 2], acc0);
            atomicAdd(&pooled[(size_t)gcur * DH + j * 2 + 1], acc1);
            acc0 = acc1 = 0.f; gcur = g;
        }
        unsigned int v = a32[(size_t)i * 64 + j];
        acc0 += fmaxf(blo(v) * sc0 + sh0, 0.f);
        acc1 += fmaxf(bhi(v) * sc1 + sh1, 0.f);
    }
    atomicAdd(&pooled[(size_t)gcur * DH + j * 2], acc0);
    atomicAdd(&pooled[(size_t)gcur * DH + j * 2 + 1], acc1);
}

// ---------------- Head ----------------

__global__ __launch_bounds__(128) void k_head(const float* __restrict__ pooled, const int* __restrict__ gcnt,
                                              const float* __restrict__ fw1, const float* __restrict__ fb1,
                                              const float* __restrict__ fw2, const float* __restrict__ fb2,
                                              float* __restrict__ out) {
    __shared__ float p[DH];
    __shared__ float z[DH];
    int g = blockIdx.x;
    int j = threadIdx.x;
    float cnt = (float)max(gcnt[g], 1);
    p[j] = pooled[(size_t)g * DH + j] / cnt;
    __syncthreads();
    float a = fb1[j];
    for (int k = 0; k < DH; k++) a += p[k] * fw1[k * DH + j];
    z[j] = fmaxf(a, 0.f);
    __syncthreads();
    if (j < DOUT) {
        float l = fb2[j];
        for (int k = 0; k < DH; k++) l += z[k] * fw2[k * DOUT + j];
        float m = l;
        for (int o = 16; o; o >>= 1) m = fmaxf(m, __shfl_xor(m, o, 32));
        float e = expf(l - m);
        float s = e;
        for (int o = 16; o; o >>= 1) s += __shfl_xor(s, o, 32);
        out[(size_t)g * DOUT + j] = e / s;
    }
}

// ---------------- launch ----------------

static inline char* align256p(char* p) {
    return (char*)(((uintptr_t)p + 255) & ~(uintptr_t)255);
}

extern "C" void kernel_launch(void* const* d_in, const int* in_sizes, int n_in,
                              void* d_out, int out_size, void* d_ws, size_t ws_size,
                              hipStream_t stream) {
    const float* x     = (const float*)d_in[0];
    const int*   ei    = (const int*)d_in[1];    // int32 per harness convention
    const int*   batch = (const int*)d_in[2];
    const float* W1    = (const float*)d_in[3];
    const float* W2    = (const float*)d_in[5];
    const float* g1    = (const float*)d_in[7];
    const float* be1   = (const float*)d_in[8];
    const float* g2    = (const float*)d_in[9];
    const float* be2   = (const float*)d_in[10];
    const float* fw1   = (const float*)d_in[11];
    const float* fb1   = (const float*)d_in[12];
    const float* fw2   = (const float*)d_in[13];
    const float* fb2   = (const float*)d_in[14];
    float* out = (float*)d_out;

    // workspace carve-up
    char* w = (char*)d_ws;
    unsigned short* hbuf = (unsigned short*)w;  w += (size_t)NN * DH * 2;
    unsigned short* abuf = (unsigned short*)w;  w += (size_t)NN * DH * 2;
    int*   csr    = (int*)w;    w += (size_t)NE * 4;
    int*   rowptr = (int*)w;    w += (size_t)(NN + 1) * 4;  w = align256p(w);
    float* dinv   = (float*)w;  w += (size_t)NN * 4;
    int*   bsum   = (int*)w;    w += 512 * 4;
    int*   bscan  = (int*)w;    w += 512 * 4;
    float* scale1 = (float*)w;  w += DH * 4;
    float* shift1 = (float*)w;  w += DH * 4;
    float* scale2 = (float*)w;  w += DH * 4;
    float* shift2 = (float*)w;  w += DH * 4;
    w = align256p(w);
    char* zstart  = w;
    int*   cnt    = (int*)w;    w += (size_t)NN * 4;   // also the fill cursor
    int*   gfirst = (int*)w;    w += 64 * 4;
    int*   glast  = (int*)w;    w += 64 * 4;
    int*   gcnt   = (int*)w;    w += 64 * 4;
    float* stats1 = (float*)w;  w += (size_t)NBUCKET * 256 * 4;
    float* stats2 = (float*)w;  w += (size_t)NBUCKET * 256 * 4;
    float* pooled = (float*)w;  w += (size_t)NG * DH * 4;
    size_t zbytes = (size_t)(w - zstart);
    size_t need = (size_t)(w - (char*)d_ws);
    if (ws_size < need) return;   // diagnostic: clean absmax-fail instead of a fault

    hipMemsetAsync(zstart, 0, zbytes, stream);

    k_count<<<1024, 256, 0, stream>>>(ei + NE, cnt);
    k_gbound<<<(NN + 255) / 256, 256, 0, stream>>>(batch, gfirst, glast);
    k_scan_partial<<<SCAN_NB, 256, 0, stream>>>(cnt, bsum);
    k_scan_top<<<1, 128, 0, stream>>>(bsum, bscan, rowptr, gfirst, glast, gcnt);
    k_scan_final<<<SCAN_NB, 256, 0, stream>>>(cnt, bscan, rowptr, dinv);
    k_fill<<<1024, 256, 0, stream>>>(ei, cnt, csr);

    int gemm_grid = (NN + 63) / 64;

    // layer 1 (output pre-scaled by dinv)
    k_gemm<false, float><<<gemm_grid, 256, 0, stream>>>(x, W1, hbuf, dinv, nullptr, nullptr);
    k_aggregate<<<8192, 128, 0, stream>>>(hbuf, rowptr, csr, dinv, abuf, stats1);
    k_bnparams<<<1, 128, 0, stream>>>(stats1, g1, be1, scale1, shift1);

    // layer 2 (BN1+ReLU fused into GEMM A-load; output pre-scaled by dinv)
    k_gemm<true, unsigned short><<<gemm_grid, 256, 0, stream>>>(abuf, W2, hbuf, dinv, scale1, shift1);
    k_aggregate<<<8192, 128, 0, stream>>>(hbuf, rowptr, csr, dinv, abuf, stats2);
    k_bnparams<<<1, 128, 0, stream>>>(stats2, g2, be2, scale2, shift2);

    // pool (BN2+ReLU fused) + head
    int pool_grid = (NN + POOL_CHUNK - 1) / POOL_CHUNK;
    k_pool<<<pool_grid, 64, 0, stream>>>(abuf, batch, scale2, shift2, pooled);
    k_head<<<NG, 128, 0, stream>>>(pooled, gcnt, fw1, fb1, fw2, fb2, out);
}

// Round 4
// 469.606 us; speedup vs baseline: 3.4896x; 1.2866x over previous
//
#include <hip/hip_runtime.h>
#include <hip/hip_bf16.h>
#include <stdint.h>

// Problem constants
#define NN 100000
#define NE 1600000
#define DH 128
#define DOUT 32
#define NG 64
#define EPS 1e-5f

#define SCAN_BLK 1024
#define SCAN_NB ((NN + SCAN_BLK - 1) / SCAN_BLK)   // 98
#define NBUCKET 32

typedef __attribute__((ext_vector_type(8))) unsigned short ushort8;
typedef __attribute__((ext_vector_type(8))) short bfv8;     // MFMA A/B fragment (8 bf16)
typedef __attribute__((ext_vector_type(4))) float f32x4;    // MFMA C/D fragment

__device__ __forceinline__ float b2f(unsigned short u) {
    return __uint_as_float(((unsigned int)u) << 16);
}
__device__ __forceinline__ unsigned int f2b(float f) {   // round-to-nearest-even, low 16 bits
    unsigned int u = __float_as_uint(f);
    return (u + 0x7fffu + ((u >> 16) & 1u)) >> 16;
}
__device__ __forceinline__ float blo(unsigned int v) { return __uint_as_float(v << 16); }
__device__ __forceinline__ float bhi(unsigned int v) { return __uint_as_float(v & 0xffff0000u); }

// ---------------- CSR build ----------------

__global__ void k_count(const int* __restrict__ ei_dst, int* __restrict__ cnt) {
    int i = blockIdx.x * blockDim.x + threadIdx.x;
    int stride = gridDim.x * blockDim.x;
    const int4* d4 = reinterpret_cast<const int4*>(ei_dst);
    for (int e = i; e < NE / 4; e += stride) {
        int4 d = d4[e];
        atomicAdd(&cnt[d.x], 1);
        atomicAdd(&cnt[d.y], 1);
        atomicAdd(&cnt[d.z], 1);
        atomicAdd(&cnt[d.w], 1);
    }
}

__global__ void k_gbound(const int* __restrict__ batch, int* __restrict__ first, int* __restrict__ last) {
    int i = blockIdx.x * blockDim.x + threadIdx.x;
    if (i >= NN) return;
    int g = batch[i];
    if (i == 0 || batch[i - 1] != g) first[g] = i;
    if (i == NN - 1 || batch[i + 1] != g) last[g] = i + 1;
}

__global__ void k_scan_partial(const int* __restrict__ cnt, int* __restrict__ bsum) {
    __shared__ int sdata[256];
    int blk = blockIdx.x, t = threadIdx.x;
    int base = blk * SCAN_BLK + t * 4;
    int s = 0;
#pragma unroll
    for (int q = 0; q < 4; q++) { int idx = base + q; if (idx < NN) s += cnt[idx]; }
    sdata[t] = s; __syncthreads();
    for (int o = 128; o; o >>= 1) { if (t < o) sdata[t] += sdata[t + o]; __syncthreads(); }
    if (t == 0) bsum[blk] = sdata[0];
}

__global__ void k_scan_top(const int* __restrict__ bsum, int* __restrict__ bscan, int* __restrict__ rowptr,
                           const int* __restrict__ first, const int* __restrict__ last, int* __restrict__ gcnt) {
    __shared__ int sd[128];
    int t = threadIdx.x;
    int v = (t < SCAN_NB) ? bsum[t] : 0;
    sd[t] = v; __syncthreads();
    for (int o = 1; o < 128; o <<= 1) {
        int add = (t >= o) ? sd[t - o] : 0;
        __syncthreads();
        sd[t] += add;
        __syncthreads();
    }
    if (t < SCAN_NB) bscan[t] = sd[t] - v;
    if (t == 127) rowptr[NN] = sd[127];
    if (t < NG) gcnt[t] = last[t] - first[t];
}

__global__ void k_scan_final(int* __restrict__ cnt, const int* __restrict__ bscan,
                             int* __restrict__ rowptr, float* __restrict__ dinv) {
    __shared__ int sdata[256];
    int blk = blockIdx.x, t = threadIdx.x;
    int base = blk * SCAN_BLK + t * 4;
    int v[4]; int s = 0;
#pragma unroll
    for (int q = 0; q < 4; q++) { int idx = base + q; v[q] = (idx < NN) ? cnt[idx] : 0; s += v[q]; }
    sdata[t] = s; __syncthreads();
    for (int o = 1; o < 256; o <<= 1) {
        int add = (t >= o) ? sdata[t - o] : 0;
        __syncthreads();
        sdata[t] += add;
        __syncthreads();
    }
    int offset = bscan[blk] + sdata[t] - s;
#pragma unroll
    for (int q = 0; q < 4; q++) {
        int idx = base + q;
        if (idx < NN) {
            rowptr[idx] = offset;
            cnt[idx] = offset;                      // cursor for k_fill
            dinv[idx] = rsqrtf((float)(v[q] + 1));  // +1 self loop
            offset += v[q];
        }
    }
}

__global__ void k_fill(const int* __restrict__ ei, int* __restrict__ cursor, int* __restrict__ csr) {
    int i = blockIdx.x * blockDim.x + threadIdx.x;
    int stride = gridDim.x * blockDim.x;
    const int4* s4 = reinterpret_cast<const int4*>(ei);
    const int4* d4 = reinterpret_cast<const int4*>(ei + NE);
    for (int e = i; e < NE / 4; e += stride) {
        int4 s = s4[e];
        int4 d = d4[e];
        csr[atomicAdd(&cursor[d.x], 1)] = s.x;
        csr[atomicAdd(&cursor[d.y], 1)] = s.y;
        csr[atomicAdd(&cursor[d.z], 1)] = s.z;
        csr[atomicAdd(&cursor[d.w], 1)] = s.w;
    }
}

// ---------------- W prep: WT[n][k] = bf16(W[k][n]) for both layers ----------------

__global__ void k_prepw(const float* __restrict__ W1, const float* __restrict__ W2,
                        unsigned short* __restrict__ WT1, unsigned short* __restrict__ WT2) {
    int i = blockIdx.x * blockDim.x + threadIdx.x;   // 0..32767
    int sel = i >> 14;
    int j = i & 16383;
    int k = j >> 7, n = j & 127;
    const float* W = sel ? W2 : W1;
    unsigned short* WT = sel ? WT2 : WT1;
    WT[n * 128 + k] = (unsigned short)f2b(W[j]);
}

// ---------------- MFMA GEMM: C[N,128](bf16) = rowscale * (transform(A)[N,128] @ W[128,128]) ----------------
// BM=128 rows/block, 256 threads = 4 waves, each wave computes 32 rows x 128 cols.
// LDS: As 128x128 bf16 (32KB, XOR-swizzled) + Ws = W^T 128x128 bf16 (32KB, swizzled). K=128 single stage.
// mfma_f32_16x16x32_bf16: A/B frag = 8 contiguous k at row/col (l&15), kgroup (l>>4); D col=l&15, row=(l>>4)*4+reg.

template <bool BN, typename AT>
__global__ __launch_bounds__(256) void k_gemm(const AT* __restrict__ A, const unsigned short* __restrict__ WTg,
                                              unsigned short* __restrict__ C, const float* __restrict__ rowscale,
                                              const float* __restrict__ scale, const float* __restrict__ shift) {
    __shared__ unsigned char lds[65536];
    unsigned char* As = lds;
    unsigned char* Ws = lds + 32768;
    int row0 = blockIdx.x * 128;
    int t = threadIdx.x;
    int l = t & 63;
    int w = t >> 6;

    // ---- stage A tile (convert to bf16, optional BN+ReLU), swizzled ----
    if constexpr (sizeof(AT) == 4) {
#pragma unroll
        for (int q = 0; q < 16; q++) {
            int idx = q * 256 + t;          // float4 index over 128x32
            int r = idx >> 5, c4 = idx & 31;
            float4 v = make_float4(0.f, 0.f, 0.f, 0.f);
            if (row0 + r < NN) v = reinterpret_cast<const float4*>(A)[(size_t)(row0 + r) * 32 + c4];
            ushort4 u;
            u.x = (unsigned short)f2b(v.x);
            u.y = (unsigned short)f2b(v.y);
            u.z = (unsigned short)f2b(v.z);
            u.w = (unsigned short)f2b(v.w);
            int off = r * 256 + ((c4 * 8) ^ ((r & 7) << 4));
            *reinterpret_cast<ushort4*>(As + off) = u;
        }
    } else {
#pragma unroll
        for (int q = 0; q < 8; q++) {
            int idx = q * 256 + t;          // ushort8 index over 128x16
            int r = idx >> 4, c8 = idx & 15;
            ushort8 v = (ushort8)0;
            if (row0 + r < NN) v = reinterpret_cast<const ushort8*>(A)[(size_t)(row0 + r) * 16 + c8];
            ushort8 u;
#pragma unroll
            for (int j = 0; j < 8; j++) {
                float f = b2f(v[j]);
                if (BN) { int k = c8 * 8 + j; f = fmaxf(f * scale[k] + shift[k], 0.f); }
                u[j] = (unsigned short)f2b(f);
            }
            int off = r * 256 + ((c8 * 16) ^ ((r & 7) << 4));
            *reinterpret_cast<ushort8*>(As + off) = u;
        }
    }
    // ---- stage W^T, swizzled ----
#pragma unroll
    for (int q = 0; q < 8; q++) {
        int idx = q * 256 + t;              // ushort8 index over 128x16
        int n = idx >> 4, c8 = idx & 15;
        ushort8 v = reinterpret_cast<const ushort8*>(WTg)[idx];
        int off = n * 256 + ((c8 * 16) ^ ((n & 7) << 4));
        *reinterpret_cast<ushort8*>(Ws + off) = v;
    }
    __syncthreads();

    f32x4 acc[2][8];
#pragma unroll
    for (int m = 0; m < 2; m++)
#pragma unroll
        for (int n = 0; n < 8; n++) acc[m][n] = (f32x4)0.f;

    int lrow = l & 15;
    int kbyte0 = (l >> 4) * 16;   // 8 bf16 = 16 bytes
#pragma unroll
    for (int kt = 0; kt < 4; kt++) {
        int kb = kt * 64 + kbyte0;
        bfv8 a[2];
#pragma unroll
        for (int m = 0; m < 2; m++) {
            int r = w * 32 + m * 16 + lrow;
            a[m] = *reinterpret_cast<const bfv8*>(As + r * 256 + (kb ^ ((r & 7) << 4)));
        }
        bfv8 b[8];
#pragma unroll
        for (int n = 0; n < 8; n++) {
            int r = n * 16 + lrow;
            b[n] = *reinterpret_cast<const bfv8*>(Ws + r * 256 + (kb ^ ((r & 7) << 4)));
        }
#pragma unroll
        for (int m = 0; m < 2; m++)
#pragma unroll
            for (int n = 0; n < 8; n++)
                acc[m][n] = __builtin_amdgcn_mfma_f32_16x16x32_bf16(a[m], b[n], acc[m][n], 0, 0, 0);
    }

    // ---- epilogue: rowscale, bf16, store ----
#pragma unroll
    for (int m = 0; m < 2; m++) {
#pragma unroll
        for (int rr = 0; rr < 4; rr++) {
            int grow = row0 + w * 32 + m * 16 + (l >> 4) * 4 + rr;
            if (grow < NN) {
                float rs = rowscale[grow];
#pragma unroll
                for (int n = 0; n < 8; n++) {
                    int col = n * 16 + (l & 15);
                    C[(size_t)grow * DH + col] = (unsigned short)f2b(acc[m][n][rr] * rs);
                }
            }
        }
    }
}

// ---------------- Aggregation: edge-balanced contiguous row ranges per wave ----------------
// agg[i] = dinv[i]*(hs[i] + sum_e hs[src]); hs pre-scaled by dinv. Bucketed BN stats.

__global__ __launch_bounds__(128) void k_aggregate(const unsigned short* __restrict__ h, const int* __restrict__ rowptr,
                                                   const int* __restrict__ csr, const float* __restrict__ dinv,
                                                   unsigned short* __restrict__ agg, float* __restrict__ stats) {
    int lane = threadIdx.x & 63;
    int wv = threadIdx.x >> 6;
    int half = lane >> 5;
    int sl = lane & 31;
    const uint2* h64 = reinterpret_cast<const uint2*>(h);
    uint2* agg64 = reinterpret_cast<uint2*>(agg);
    int wid = blockIdx.x * 2 + wv;
    int nw = gridDim.x * 2;
    long long tlo = ((long long)wid * NE) / nw;
    long long thi = (wid == nw - 1) ? (long long)NE + 1 : (((long long)(wid + 1) * NE) / nw);

    // lower_bound: first row r with rowptr[r] >= tlo
    int lo = 0, hi = NN;
    while (lo < hi) {
        int mid = (lo + hi) >> 1;
        if (rowptr[mid] < (int)tlo) lo = mid + 1; else hi = mid;
    }

    float s0 = 0.f, s1 = 0.f, s2 = 0.f, s3 = 0.f;
    float q0 = 0.f, q1 = 0.f, q2 = 0.f, q3 = 0.f;
    for (int i = lo; i < NN; i++) {
        int row = rowptr[i];
        if (row >= (int)thi) break;
        int end = rowptr[i + 1];
        int len = end - row;
        float di = dinv[i];
        float a0 = 0.f, a1 = 0.f, a2 = 0.f, a3 = 0.f;
        if (half == 0) {
            uint2 sv = h64[(size_t)i * 32 + sl];
            a0 = blo(sv.x); a1 = bhi(sv.x); a2 = blo(sv.y); a3 = bhi(sv.y);
        }
        int hc = (len + 1 - half) >> 1;   // this half-stream's edge count
        int tt = 0;
        for (; tt + 4 <= hc; tt += 4) {
            int eA = row + (tt << 1) + half;
            int n0 = csr[eA], n1 = csr[eA + 2], n2 = csr[eA + 4], n3 = csr[eA + 6];
            uint2 v0 = h64[(size_t)n0 * 32 + sl];
            uint2 v1 = h64[(size_t)n1 * 32 + sl];
            uint2 v2 = h64[(size_t)n2 * 32 + sl];
            uint2 v3 = h64[(size_t)n3 * 32 + sl];
            a0 += blo(v0.x); a1 += bhi(v0.x); a2 += blo(v0.y); a3 += bhi(v0.y);
            a0 += blo(v1.x); a1 += bhi(v1.x); a2 += blo(v1.y); a3 += bhi(v1.y);
            a0 += blo(v2.x); a1 += bhi(v2.x); a2 += blo(v2.y); a3 += bhi(v2.y);
            a0 += blo(v3.x); a1 += bhi(v3.x); a2 += blo(v3.y); a3 += bhi(v3.y);
        }
        for (; tt < hc; tt++) {
            int e = row + (tt << 1) + half;
            int n = csr[e];
            uint2 v = h64[(size_t)n * 32 + sl];
            a0 += blo(v.x); a1 += bhi(v.x); a2 += blo(v.y); a3 += bhi(v.y);
        }
        a0 += __shfl_xor(a0, 32);
        a1 += __shfl_xor(a1, 32);
        a2 += __shfl_xor(a2, 32);
        a3 += __shfl_xor(a3, 32);
        a0 *= di; a1 *= di; a2 *= di; a3 *= di;
        if (half == 0) {
            uint2 o;
            o.x = f2b(a0) | (f2b(a1) << 16);
            o.y = f2b(a2) | (f2b(a3) << 16);
            agg64[(size_t)i * 32 + sl] = o;
            s0 += a0; q0 += a0 * a0;
            s1 += a1; q1 += a1 * a1;
            s2 += a2; q2 += a2 * a2;
            s3 += a3; q3 += a3 * a3;
        }
    }
    if (half == 0) {
        float* b = stats + (size_t)(wid & (NBUCKET - 1)) * 256;
        atomicAdd(&b[sl * 4 + 0], s0);
        atomicAdd(&b[sl * 4 + 1], s1);
        atomicAdd(&b[sl * 4 + 2], s2);
        atomicAdd(&b[sl * 4 + 3], s3);
        atomicAdd(&b[128 + sl * 4 + 0], q0);
        atomicAdd(&b[128 + sl * 4 + 1], q1);
        atomicAdd(&b[128 + sl * 4 + 2], q2);
        atomicAdd(&b[128 + sl * 4 + 3], q3);
    }
}

__global__ void k_bnparams(const float* __restrict__ stats, const float* __restrict__ gamma,
                           const float* __restrict__ beta, float* __restrict__ scale, float* __restrict__ shift) {
    int j = threadIdx.x;
    float su = 0.f, sq = 0.f;
    for (int b = 0; b < NBUCKET; b++) { su += stats[b * 256 + j]; sq += stats[b * 256 + 128 + j]; }
    float mu = su * (1.f / NN);
    float var = sq * (1.f / NN) - mu * mu;
    float rs = rsqrtf(var + EPS);
    float sc = rs * gamma[j];
    scale[j] = sc;
    shift[j] = beta[j] - mu * sc;
}

// ---------------- Pool ----------------

#define POOL_CHUNK 64

__global__ __launch_bounds__(64) void k_pool(const unsigned short* __restrict__ agg, const int* __restrict__ batch,
                                             const float* __restrict__ scale, const float* __restrict__ shift,
                                             float* __restrict__ pooled) {
    int j = threadIdx.x;               // feature pair index (2j, 2j+1)
    const unsigned int* a32 = reinterpret_cast<const unsigned int*>(agg);
    int n0 = blockIdx.x * POOL_CHUNK;
    int n1 = n0 + POOL_CHUNK; if (n1 > NN) n1 = NN;
    float sc0 = scale[j * 2], sh0 = shift[j * 2];
    float sc1 = scale[j * 2 + 1], sh1 = shift[j * 2 + 1];
    int gcur = batch[n0];
    float acc0 = 0.f, acc1 = 0.f;
    for (int i = n0; i < n1; i++) {
        int g = batch[i];
        if (g != gcur) {
            atomicAdd(&pooled[(size_t)gcur * DH + j * 2], acc0);
            atomicAdd(&pooled[(size_t)gcur * DH + j * 2 + 1], acc1);
            acc0 = acc1 = 0.f; gcur = g;
        }
        unsigned int v = a32[(size_t)i * 64 + j];
        acc0 += fmaxf(blo(v) * sc0 + sh0, 0.f);
        acc1 += fmaxf(bhi(v) * sc1 + sh1, 0.f);
    }
    atomicAdd(&pooled[(size_t)gcur * DH + j * 2], acc0);
    atomicAdd(&pooled[(size_t)gcur * DH + j * 2 + 1], acc1);
}

// ---------------- Head ----------------

__global__ __launch_bounds__(128) void k_head(const float* __restrict__ pooled, const int* __restrict__ gcnt,
                                              const float* __restrict__ fw1, const float* __restrict__ fb1,
                                              const float* __restrict__ fw2, const float* __restrict__ fb2,
                                              float* __restrict__ out) {
    __shared__ float p[DH];
    __shared__ float z[DH];
    int g = blockIdx.x;
    int j = threadIdx.x;
    float cnt = (float)max(gcnt[g], 1);
    p[j] = pooled[(size_t)g * DH + j] / cnt;
    __syncthreads();
    float a = fb1[j];
    for (int k = 0; k < DH; k++) a += p[k] * fw1[k * DH + j];
    z[j] = fmaxf(a, 0.f);
    __syncthreads();
    if (j < DOUT) {
        float l = fb2[j];
        for (int k = 0; k < DH; k++) l += z[k] * fw2[k * DOUT + j];
        float m = l;
        for (int o = 16; o; o >>= 1) m = fmaxf(m, __shfl_xor(m, o, 32));
        float e = expf(l - m);
        float s = e;
        for (int o = 16; o; o >>= 1) s += __shfl_xor(s, o, 32);
        out[(size_t)g * DOUT + j] = e / s;
    }
}

// ---------------- launch ----------------

static inline char* align256p(char* p) {
    return (char*)(((uintptr_t)p + 255) & ~(uintptr_t)255);
}

extern "C" void kernel_launch(void* const* d_in, const int* in_sizes, int n_in,
                              void* d_out, int out_size, void* d_ws, size_t ws_size,
                              hipStream_t stream) {
    const float* x     = (const float*)d_in[0];
    const int*   ei    = (const int*)d_in[1];    // int32 per harness convention
    const int*   batch = (const int*)d_in[2];
    const float* W1    = (const float*)d_in[3];
    const float* W2    = (const float*)d_in[5];
    const float* g1    = (const float*)d_in[7];
    const float* be1   = (const float*)d_in[8];
    const float* g2    = (const float*)d_in[9];
    const float* be2   = (const float*)d_in[10];
    const float* fw1   = (const float*)d_in[11];
    const float* fb1   = (const float*)d_in[12];
    const float* fw2   = (const float*)d_in[13];
    const float* fb2   = (const float*)d_in[14];
    float* out = (float*)d_out;

    // workspace carve-up
    char* w = (char*)d_ws;
    unsigned short* hbuf = (unsigned short*)w;  w += (size_t)NN * DH * 2;
    unsigned short* abuf = (unsigned short*)w;  w += (size_t)NN * DH * 2;
    int*   csr    = (int*)w;    w += (size_t)NE * 4;
    int*   rowptr = (int*)w;    w += (size_t)(NN + 1) * 4;  w = align256p(w);
    float* dinv   = (float*)w;  w += (size_t)NN * 4;
    int*   bsum   = (int*)w;    w += 512 * 4;
    int*   bscan  = (int*)w;    w += 512 * 4;
    float* scale1 = (float*)w;  w += DH * 4;
    float* shift1 = (float*)w;  w += DH * 4;
    float* scale2 = (float*)w;  w += DH * 4;
    float* shift2 = (float*)w;  w += DH * 4;
    unsigned short* WT1g = (unsigned short*)w;  w += (size_t)DH * DH * 2;
    unsigned short* WT2g = (unsigned short*)w;  w += (size_t)DH * DH * 2;
    w = align256p(w);
    char* zstart  = w;
    int*   cnt    = (int*)w;    w += (size_t)NN * 4;   // also the fill cursor
    int*   gfirst = (int*)w;    w += 64 * 4;
    int*   glast  = (int*)w;    w += 64 * 4;
    int*   gcnt   = (int*)w;    w += 64 * 4;
    float* stats1 = (float*)w;  w += (size_t)NBUCKET * 256 * 4;
    float* stats2 = (float*)w;  w += (size_t)NBUCKET * 256 * 4;
    float* pooled = (float*)w;  w += (size_t)NG * DH * 4;
    size_t zbytes = (size_t)(w - zstart);
    size_t need = (size_t)(w - (char*)d_ws);
    if (ws_size < need) return;   // diagnostic: clean absmax-fail instead of a fault

    hipMemsetAsync(zstart, 0, zbytes, stream);

    k_prepw<<<128, 256, 0, stream>>>(W1, W2, WT1g, WT2g);
    k_count<<<1024, 256, 0, stream>>>(ei + NE, cnt);
    k_gbound<<<(NN + 255) / 256, 256, 0, stream>>>(batch, gfirst, glast);
    k_scan_partial<<<SCAN_NB, 256, 0, stream>>>(cnt, bsum);
    k_scan_top<<<1, 128, 0, stream>>>(bsum, bscan, rowptr, gfirst, glast, gcnt);
    k_scan_final<<<SCAN_NB, 256, 0, stream>>>(cnt, bscan, rowptr, dinv);
    k_fill<<<1024, 256, 0, stream>>>(ei, cnt, csr);

    int gemm_grid = (NN + 127) / 128;   // 782

    // layer 1 (output pre-scaled by dinv)
    k_gemm<false, float><<<gemm_grid, 256, 0, stream>>>(x, WT1g, hbuf, dinv, nullptr, nullptr);
    k_aggregate<<<4096, 128, 0, stream>>>(hbuf, rowptr, csr, dinv, abuf, stats1);
    k_bnparams<<<1, 128, 0, stream>>>(stats1, g1, be1, scale1, shift1);

    // layer 2 (BN1+ReLU fused into GEMM A-load; output pre-scaled by dinv)
    k_gemm<true, unsigned short><<<gemm_grid, 256, 0, stream>>>(abuf, WT2g, hbuf, dinv, scale1, shift1);
    k_aggregate<<<4096, 128, 0, stream>>>(hbuf, rowptr, csr, dinv, abuf, stats2);
    k_bnparams<<<1, 128, 0, stream>>>(stats2, g2, be2, scale2, shift2);

    // pool (BN2+ReLU fused) + head
    int pool_grid = (NN + POOL_CHUNK - 1) / POOL_CHUNK;
    k_pool<<<pool_grid, 64, 0, stream>>>(abuf, batch, scale2, shift2, pooled);
    k_head<<<NG, 128, 0, stream>>>(pooled, gcnt, fw1, fb1, fw2, fb2, out);
}